// Round 13
// baseline (293.894 us; speedup 1.0000x reference)
//
#include <hip/hip_runtime.h>
#include <hip/hip_bf16.h>
#include <cstdint>
#include <cstddef>
#include <cstring>

// Problem constants
#define HDIM 256
#define EDIM 512
#define NB   2
#define NSQ  512
#define NSK  512

typedef _Float16 f16x8 __attribute__((ext_vector_type(8)));
typedef _Float16 h2    __attribute__((ext_vector_type(2)));
typedef __fp16   fp16v2 __attribute__((ext_vector_type(2)));
typedef float    f32x4  __attribute__((ext_vector_type(4)));

// Workspace layout (ushort elements). All weights in 16x16x32 A-frag layout:
// frag[t][s][lane][j8] = W[(s*32 + (lane>>4)*8 + j)*256 + t*16 + (lane&15)]
#define OFF_W2F  0u
#define OFF_W3F  65536u
#define OFF_WQEF 131072u
#define OFF_WKEF 262144u
#define OFF_WCQ  393216u
#define OFF_WCK  524288u
#define OFF_WV2H 655360u     // 256 f16
#define F16_WS_END_BYTES 1312768u

union U8 { f16x8 v; h2 h[4]; };

// packed RTZ f32x2 -> f16x2 (v_cvt_pkrtz_f16_f32)
__device__ __forceinline__ ushort2 f2h2(float x, float y) {
  fp16v2 r = __builtin_amdgcn_cvt_pkrtz(x, y);
  ushort2 u;
  __builtin_memcpy(&u, &r, 4);
  return u;
}
__device__ __forceinline__ float relu_(float x) { return x > 0.f ? x : 0.f; }
__device__ __forceinline__ float softplus_(float x) {
  return fmaxf(x, 0.f) + log1pf(expf(-fabsf(x)));
}

// ---------------------------------------------------------------------------
// K1: shuffle fp32 weights -> f16 MFMA A-frag order via LDS transpose.
// Blocks: 0-7 W2 | 8-15 W3 | 16-31 Wqe | 32-47 Wke |
//         48-55 W1top | 56-63 Wv1top | 64-71 W1bot | 72-79 Wv1bot | 80 Wv2
// ---------------------------------------------------------------------------
__global__ __launch_bounds__(256) void shuffle_weights(
    const float* __restrict__ Wqe, const float* __restrict__ Wke,
    const float* __restrict__ W1,  const float* __restrict__ Wv1,
    const float* __restrict__ W2,  const float* __restrict__ W3,
    const float* __restrict__ Wv2,
    unsigned short* __restrict__ wsb)
{
  __shared__ float sW[32 * 257];   // pad +1: transpose reads 2-way max (free)
  const int bx = blockIdx.x;
  const int t = threadIdx.x;
  if (bx == 80) {
    if (t < 64) {
      float a = Wv2[t * 4 + 0], b = Wv2[t * 4 + 1];
      float c = Wv2[t * 4 + 2], d = Wv2[t * 4 + 3];
      ushort2 lo = f2h2(a, b), hi = f2h2(c, d);
      ushort4 o; o.x = lo.x; o.y = lo.y; o.z = hi.x; o.w = hi.y;
      *(ushort4*)&wsb[OFF_WV2H + t * 4] = o;
    }
    return;
  }
  const float* src; unsigned short* dst; int s; int S;
  if      (bx <  8) { src = W2;          dst = wsb + OFF_W2F;           s = bx;      S = 8;  }
  else if (bx < 16) { src = W3;          dst = wsb + OFF_W3F;           s = bx - 8;  S = 8;  }
  else if (bx < 32) { src = Wqe;         dst = wsb + OFF_WQEF;          s = bx - 16; S = 16; }
  else if (bx < 48) { src = Wke;         dst = wsb + OFF_WKEF;          s = bx - 32; S = 16; }
  else if (bx < 56) { src = W1;          dst = wsb + OFF_WCQ;           s = bx - 48; S = 8;  }
  else if (bx < 64) { src = Wv1;         dst = wsb + OFF_WCQ + 65536u;  s = bx - 56; S = 8;  }
  else if (bx < 72) { src = W1 + 65536;  dst = wsb + OFF_WCK;           s = bx - 64; S = 8;  }
  else              { src = Wv1 + 65536; dst = wsb + OFF_WCK + 65536u;  s = bx - 72; S = 8;  }

  const int kbase = s * 32;
  #pragma unroll
  for (int it = 0; it < 8; ++it) {
    const int f4 = it * 256 + t;
    const int row = f4 >> 6, c4 = (f4 & 63) * 4;
    float4 v = *(const float4*)(src + (size_t)(kbase + row) * 256 + c4);
    sW[row * 257 + c4 + 0] = v.x; sW[row * 257 + c4 + 1] = v.y;
    sW[row * 257 + c4 + 2] = v.z; sW[row * 257 + c4 + 3] = v.w;
  }
  __syncthreads();

  const int wave = t >> 6, lane = t & 63;
  const int n_in = lane & 15, k0 = (lane >> 4) * 8;
  for (int tt = wave * 4; tt < wave * 4 + 4; ++tt) {
    const int n = tt * 16 + n_in;
    float x[8];
    #pragma unroll
    for (int j = 0; j < 8; ++j) x[j] = sW[(k0 + j) * 257 + n];
    ushort2 p0 = f2h2(x[0], x[1]), p1 = f2h2(x[2], x[3]);
    ushort2 p2 = f2h2(x[4], x[5]), p3 = f2h2(x[6], x[7]);
    ushort4 lo; lo.x = p0.x; lo.y = p0.y; lo.z = p1.x; lo.w = p1.y;
    ushort4 hi; hi.x = p2.x; hi.y = p2.y; hi.z = p3.x; hi.w = p3.y;
    unsigned short* o = dst + ((size_t)(tt * S + s) * 64 + lane) * 8;
    *(ushort4*)&o[0] = lo; *(ushort4*)&o[4] = hi;
  }
}

// ---------------------------------------------------------------------------
// K2: encoder + projections (16x16x32 f16 MFMA). 256 blocks: (side, rt16, nh).
// Full GEMM1 (duplicated across the 2 nh blocks — cheap), half of GEMM2's
// 32 n-tiles per block. A-loads double-buffered in both loops.
// ---------------------------------------------------------------------------
__global__ __launch_bounds__(256) void encoder_kernel(
    const float* __restrict__ query, const float* __restrict__ key,
    const float* __restrict__ bqe,   const float* __restrict__ bke,
    const float* __restrict__ b1,    const float* __restrict__ bv1,
    const unsigned short* __restrict__ WqeF, const unsigned short* __restrict__ WkeF,
    const unsigned short* __restrict__ WcqF, const unsigned short* __restrict__ WckF,
    _Float16* __restrict__ Pq, _Float16* __restrict__ Pk)
{
  __shared__ unsigned short sX[16 * 520];
  __shared__ unsigned short sF[16 * 264];
  __shared__ float sBe[256];
  __shared__ float sBc[512];

  const int bx   = blockIdx.x;
  const int side = bx >> 7;
  const int idx  = bx & 127;
  const int rt   = idx >> 1;
  const int nh   = idx & 1;
  const int t    = threadIdx.x;

  const float* Xsrc = side ? key : query;
  const unsigned short* WeF = side ? WkeF : WqeF;
  const unsigned short* WcF = side ? WckF : WcqF;
  _Float16* P = side ? Pk : Pq;

  {
    const int m = t >> 4, ch = t & 15;
    const float* xr = Xsrc + (size_t)(rt * 16 + m) * EDIM;
    #pragma unroll
    for (int j = 0; j < 4; ++j) {
      const int c = ch * 32 + j * 8;
      float4 v0 = *(const float4*)(xr + c);
      float4 v1 = *(const float4*)(xr + c + 4);
      ushort2 p0 = f2h2(v0.x, v0.y), p1 = f2h2(v0.z, v0.w);
      ushort2 p2 = f2h2(v1.x, v1.y), p3 = f2h2(v1.z, v1.w);
      ushort4 lo; lo.x = p0.x; lo.y = p0.y; lo.z = p1.x; lo.w = p1.y;
      ushort4 hi; hi.x = p2.x; hi.y = p2.y; hi.z = p3.x; hi.w = p3.y;
      *(ushort4*)&sX[m * 520 + c] = lo;
      *(ushort4*)&sX[m * 520 + c + 4] = hi;
    }
    sBe[t]       = side ? bke[t] : bqe[t];
    sBc[t]       = side ? 0.f : b1[t];
    sBc[256 + t] = side ? 0.f : bv1[t];
  }

  const int wave = t >> 6, lane = t & 63;
  const int l15 = lane & 15, q4 = lane >> 4;

  const unsigned short* aeb = WeF + ((size_t)(wave * 4) * 16 * 64 + lane) * 8;
  f16x8 afe[2][4];
  #pragma unroll
  for (int ft = 0; ft < 4; ++ft)
    afe[0][ft] = *(const f16x8*)(aeb + ft * 8192);

  __syncthreads();

  f32x4 acc1[4];
  #pragma unroll
  for (int ft = 0; ft < 4; ++ft) acc1[ft] = (f32x4){0.f, 0.f, 0.f, 0.f};

  #pragma unroll
  for (int s = 0; s < 16; ++s) {
    if (s < 15) {
      #pragma unroll
      for (int ft = 0; ft < 4; ++ft)
        afe[(s + 1) & 1][ft] = *(const f16x8*)(aeb + ft * 8192 + (size_t)(s + 1) * 512);
    }
    f16x8 bfr = *(const f16x8*)&sX[l15 * 520 + s * 32 + q4 * 8];
    #pragma unroll
    for (int ft = 0; ft < 4; ++ft)
      acc1[ft] = __builtin_amdgcn_mfma_f32_16x16x32_f16(afe[s & 1][ft], bfr, acc1[ft], 0, 0, 0);
  }

  #pragma unroll
  for (int ft = 0; ft < 4; ++ft) {
    const int tg = wave * 4 + ft;
    const int n0 = tg * 16 + q4 * 4;
    float4 b4 = *(const float4*)&sBe[n0];
    f32x4 a = acc1[ft];
    ushort2 lo = f2h2(relu_(a[0] + b4.x), relu_(a[1] + b4.y));
    ushort2 hi = f2h2(relu_(a[2] + b4.z), relu_(a[3] + b4.w));
    ushort4 h; h.x = lo.x; h.y = lo.y; h.z = hi.x; h.w = hi.y;
    *(ushort4*)&sF[l15 * 264 + n0] = h;
  }
  __syncthreads();

  const unsigned short* acb = WcF + ((size_t)(nh * 16 + wave * 4) * 8 * 64 + lane) * 8;
  f16x8 afc[2][4];
  #pragma unroll
  for (int ft = 0; ft < 4; ++ft)
    afc[0][ft] = *(const f16x8*)(acb + ft * 4096);

  f32x4 acc2[4];
  #pragma unroll
  for (int ft = 0; ft < 4; ++ft) acc2[ft] = (f32x4){0.f, 0.f, 0.f, 0.f};

  #pragma unroll
  for (int s = 0; s < 8; ++s) {
    if (s < 7) {
      #pragma unroll
      for (int ft = 0; ft < 4; ++ft)
        afc[(s + 1) & 1][ft] = *(const f16x8*)(acb + ft * 4096 + (size_t)(s + 1) * 512);
    }
    f16x8 bfr = *(const f16x8*)&sF[l15 * 264 + s * 32 + q4 * 8];
    #pragma unroll
    for (int ft = 0; ft < 4; ++ft)
      acc2[ft] = __builtin_amdgcn_mfma_f32_16x16x32_f16(afc[s & 1][ft], bfr, acc2[ft], 0, 0, 0);
  }

  #pragma unroll
  for (int ft = 0; ft < 4; ++ft) {
    const int tg = nh * 16 + wave * 4 + ft;
    const int n0 = tg * 16 + q4 * 4;
    float4 bc = *(const float4*)&sBc[n0];
    const int row = rt * 16 + l15;
    f32x4 a = acc2[ft];
    ushort2 lo = f2h2(a[0] + bc.x, a[1] + bc.y);
    ushort2 hi = f2h2(a[2] + bc.z, a[3] + bc.w);
    ushort4 o; o.x = lo.x; o.y = lo.y; o.z = hi.x; o.w = hi.y;
    *(ushort4*)((unsigned short*)P + (size_t)row * 512 + n0) = o;
  }
}

// ---------------------------------------------------------------------------
// K3: fused pair kernel — R12 structure, retuned for 3 blocks/CU:
//  - B-register-prefetch REMOVED (it cost ~32 VGPR; R8 without it = 52 VGPR.
//    52 VGPR + 32 AGPR = 84 <= 512/6 — fits 6 waves/SIMD = 3 blocks/CU).
//  - __launch_bounds__(512, 6) requests that occupancy. Unlike R3, the
//    budget (85) >= need (84), so no spill expected — check WRITE_SIZE.
//  - dedicated sRed (4 barriers), split fdot2, late variance store kept.
// Rationale: barrier drains stall one block's 8 waves; with 3 resident
// blocks 2/3 of the CU keeps flowing vs 1/2 at 2 blocks. LDS 38912*3 =
// 117 KB <= 160 KB.
// ---------------------------------------------------------------------------
__global__ __launch_bounds__(512, 6) void pair_kernel(
    const _Float16* __restrict__ Pq, const _Float16* __restrict__ Pk,
    const unsigned short* __restrict__ W2F, const unsigned short* __restrict__ W3F,
    const float* __restrict__ b2, const float* __restrict__ b3,
    const float* __restrict__ Wf, const float* __restrict__ bfp,
    const unsigned short* __restrict__ Wv2H, const float* __restrict__ bv2p,
    float* __restrict__ out)
{
  __shared__ __align__(16) unsigned char smem[38912];
  unsigned short* sXH = (unsigned short*)smem;        // 64*264 f16 = 33792 B
  float* sB2  = (float*)(smem + 33792);               // 1024 B
  float* sB3  = (float*)(smem + 34816);               // 1024 B
  float* sWf  = (float*)(smem + 35840);               // 1024 B
  float* sRed = (float*)(smem + 36864);               // 8*64*4 = 2048 B (own)

  const int kt = blockIdx.x, qy = blockIdx.y, bz = blockIdx.z;
  const int t = threadIdx.x;
  const _Float16* qpRow = Pq + (size_t)(bz * NSQ + qy) * 512;

  const int wave = t >> 6, lane = t & 63;
  const int l15 = lane & 15, q4 = lane >> 4;

  // A-fragment bases (n-tiles 2w, 2w+1), s-stride 512 ushorts.
  const unsigned short* a2base = W2F + ((size_t)(wave * 2) * 8 * 64 + lane) * 8;
  const unsigned short* a3base = W3F + ((size_t)(wave * 2) * 8 * 64 + lane) * 8;

  // Issue s=0 A-loads for GEMM1 before staging.
  f16x8 afd[2][2];
  afd[0][0] = *(const f16x8*)(a2base);
  afd[0][1] = *(const f16x8*)(a2base + 8 * 64 * 8);

  // --- staging: X1 = relu(qp+kp) (packed f16, pad-264) + variance fdot2 ---
  float vp0 = 0.f, vp1 = 0.f;
  {
    const int m   = t >> 3;     // 0..63 pair row
    const int sub = t & 7;      // 0..7
    const _Float16* kpRow = Pk + (size_t)(bz * NSK + kt * 64 + m) * 512;
    const f16x8 z8 = {0, 0, 0, 0, 0, 0, 0, 0};
    #pragma unroll
    for (int it = 0; it < 4; ++it) {
      const int c = it * 64 + sub * 8;
      f16x8 q8 = *(const f16x8*)(qpRow + c);
      f16x8 k8 = *(const f16x8*)(kpRow + c);
      f16x8 r  = __builtin_elementwise_max(q8 + k8, z8);
      *(f16x8*)&sXH[m * 264 + c] = r;
      f16x8 a8 = *(const f16x8*)(qpRow + 256 + c);
      f16x8 v8 = *(const f16x8*)(kpRow + 256 + c);
      U8 ar; ar.v = __builtin_elementwise_max(a8 + v8, z8);
      U8 w8; w8.v = *(const f16x8*)((const _Float16*)Wv2H + c);
      vp0 = __builtin_amdgcn_fdot2(ar.h[0], w8.h[0], vp0, false);
      vp1 = __builtin_amdgcn_fdot2(ar.h[1], w8.h[1], vp1, false);
      vp0 = __builtin_amdgcn_fdot2(ar.h[2], w8.h[2], vp0, false);
      vp1 = __builtin_amdgcn_fdot2(ar.h[3], w8.h[3], vp1, false);
    }
    if (t < 256) { sB2[t] = b2[t]; sB3[t] = b3[t]; sWf[t] = Wf[t]; }
  }
  __syncthreads();

  // --- GEMM1: D1[n][m] = sum_k W2[k][n] * X1[m][k], A dbuf ---
  f32x4 acc[2][4];
  #pragma unroll
  for (int ft = 0; ft < 2; ++ft)
    #pragma unroll
    for (int pt = 0; pt < 4; ++pt)
      acc[ft][pt] = (f32x4){0.f, 0.f, 0.f, 0.f};

  #pragma unroll
  for (int s = 0; s < 8; ++s) {
    if (s < 7) {
      afd[(s + 1) & 1][0] = *(const f16x8*)(a2base + (size_t)(s + 1) * 512);
      afd[(s + 1) & 1][1] = *(const f16x8*)(a2base + 8 * 64 * 8 + (size_t)(s + 1) * 512);
    }
    f16x8 bfr[4];
    #pragma unroll
    for (int pt = 0; pt < 4; ++pt)
      bfr[pt] = *(const f16x8*)&sXH[(pt * 16 + l15) * 264 + s * 32 + q4 * 8];
    #pragma unroll
    for (int ft = 0; ft < 2; ++ft)
      #pragma unroll
      for (int pt = 0; pt < 4; ++pt)
        acc[ft][pt] = __builtin_amdgcn_mfma_f32_16x16x32_f16(afd[s & 1][ft], bfr[pt], acc[ft][pt], 0, 0, 0);
  }
  __syncthreads();   // all X1 reads done before overwrite

  // Prefetch GEMM2 s=0 A-frags during epilogue 1.
  afd[0][0] = *(const f16x8*)(a3base);
  afd[0][1] = *(const f16x8*)(a3base + 8 * 64 * 8);

  // --- Epilogue 1: H1 = relu(D1 + b2) -> f16, same LDS (pad-264) ---
  #pragma unroll
  for (int ft = 0; ft < 2; ++ft) {
    const int tg = wave * 2 + ft;
    const int n0 = tg * 16 + q4 * 4;
    float4 b4 = *(const float4*)&sB2[n0];
    #pragma unroll
    for (int pt = 0; pt < 4; ++pt) {
      const int mr = pt * 16 + l15;
      f32x4 a = acc[ft][pt];
      ushort2 lo = f2h2(relu_(a[0] + b4.x), relu_(a[1] + b4.y));
      ushort2 hi = f2h2(relu_(a[2] + b4.z), relu_(a[3] + b4.w));
      ushort4 h; h.x = lo.x; h.y = lo.y; h.z = hi.x; h.w = hi.y;
      *(ushort4*)&sXH[mr * 264 + n0] = h;
    }
  }
  __syncthreads();

  // --- GEMM2: D2[n][m] = sum_k W3[k][n] * H1[m][k], A dbuf ---
  f32x4 acc2[2][4];
  #pragma unroll
  for (int ft = 0; ft < 2; ++ft)
    #pragma unroll
    for (int pt = 0; pt < 4; ++pt)
      acc2[ft][pt] = (f32x4){0.f, 0.f, 0.f, 0.f};

  #pragma unroll
  for (int s = 0; s < 8; ++s) {
    if (s < 7) {
      afd[(s + 1) & 1][0] = *(const f16x8*)(a3base + (size_t)(s + 1) * 512);
      afd[(s + 1) & 1][1] = *(const f16x8*)(a3base + 8 * 64 * 8 + (size_t)(s + 1) * 512);
    }
    f16x8 bfr[4];
    #pragma unroll
    for (int pt = 0; pt < 4; ++pt)
      bfr[pt] = *(const f16x8*)&sXH[(pt * 16 + l15) * 264 + s * 32 + q4 * 8];
    #pragma unroll
    for (int ft = 0; ft < 2; ++ft)
      #pragma unroll
      for (int pt = 0; pt < 4; ++pt)
        acc2[ft][pt] = __builtin_amdgcn_mfma_f32_16x16x32_f16(afd[s & 1][ft], bfr[pt], acc2[ft][pt], 0, 0, 0);
  }

  // --- variance head: reduce + store (off the staging critical path) ---
  {
    float v = vp0 + vp1;
    v += __shfl_xor(v, 1, 64);
    v += __shfl_xor(v, 2, 64);
    v += __shfl_xor(v, 4, 64);
    if ((t & 7) == 0) {
      const int m = t >> 3;
      const size_t o = (size_t)(bz * NSQ + qy) * NSK + kt * 64 + m;
      out[(size_t)NB * NSQ * NSK + o] = softplus_(v + bv2p[0]);
    }
  }

  // --- Final epilogue: logit partials over this wave's 32 n-cols ---
  float p[4] = {0.f, 0.f, 0.f, 0.f};
  #pragma unroll
  for (int ft = 0; ft < 2; ++ft) {
    const int tg = wave * 2 + ft;
    const int n0 = tg * 16 + q4 * 4;
    float4 b4 = *(const float4*)&sB3[n0];
    float4 w4 = *(const float4*)&sWf[n0];
    #pragma unroll
    for (int pt = 0; pt < 4; ++pt) {
      f32x4 a = acc2[ft][pt];
      p[pt] += relu_(a[0] + b4.x) * w4.x + relu_(a[1] + b4.y) * w4.y
             + relu_(a[2] + b4.z) * w4.z + relu_(a[3] + b4.w) * w4.w;
    }
  }
  // sRed is its own buffer — no barrier needed before writing it.
  #pragma unroll
  for (int pt = 0; pt < 4; ++pt) {
    float v = p[pt];
    v += __shfl_xor(v, 16, 64);
    v += __shfl_xor(v, 32, 64);
    if (lane < 16) sRed[wave * 64 + pt * 16 + lane] = v;
  }
  __syncthreads();

  if (t < 64) {
    const size_t o = (size_t)(bz * NSQ + qy) * NSK + kt * 64 + t;
    float lg = bfp[0];
    #pragma unroll
    for (int w = 0; w < 8; ++w) lg += sRed[w * 64 + t];
    out[o] = lg;
  }
}

// ---------------------------------------------------------------------------
extern "C" void kernel_launch(void* const* d_in, const int* in_sizes, int n_in,
                              void* d_out, int out_size, void* d_ws, size_t ws_size,
                              hipStream_t stream)
{
  (void)in_sizes; (void)n_in; (void)out_size; (void)ws_size;
  const float* query = (const float*)d_in[0];
  const float* key   = (const float*)d_in[1];
  const float* Wqe   = (const float*)d_in[2];
  const float* bqe   = (const float*)d_in[3];
  const float* Wke   = (const float*)d_in[4];
  const float* bke   = (const float*)d_in[5];
  const float* W1    = (const float*)d_in[6];
  const float* b1    = (const float*)d_in[7];
  const float* W2    = (const float*)d_in[8];
  const float* b2    = (const float*)d_in[9];
  const float* W3    = (const float*)d_in[10];
  const float* b3    = (const float*)d_in[11];
  const float* Wf    = (const float*)d_in[12];
  const float* bf    = (const float*)d_in[13];
  const float* Wv1   = (const float*)d_in[14];
  const float* bv1   = (const float*)d_in[15];
  const float* Wv2   = (const float*)d_in[16];
  const float* bv2   = (const float*)d_in[17];

  unsigned short* wsb = (unsigned short*)d_ws;
  _Float16* Pq = (_Float16*)((char*)d_ws + F16_WS_END_BYTES);   // [1024][512] f16
  _Float16* Pk = Pq + (size_t)1024 * 512;                       // [1024][512] f16
  float* out = (float*)d_out;

  shuffle_weights<<<81, 256, 0, stream>>>(Wqe, Wke, W1, Wv1, W2, W3, Wv2, wsb);
  encoder_kernel<<<256, 256, 0, stream>>>(query, key, bqe, bke, b1, bv1,
      wsb + OFF_WQEF, wsb + OFF_WKEF, wsb + OFF_WCQ, wsb + OFF_WCK, Pq, Pk);
  pair_kernel<<<dim3(NSK / 64, NSQ, NB), 512, 0, stream>>>(Pq, Pk,
      wsb + OFF_W2F, wsb + OFF_W3F, b2, b3, Wf, bf, wsb + OFF_WV2H, bv2, out);
}

// Round 15
// 255.268 us; speedup vs baseline: 1.1513x; 1.1513x over previous
//
#include <hip/hip_runtime.h>
#include <hip/hip_bf16.h>
#include <cstdint>
#include <cstddef>
#include <cstring>

// Problem constants
#define HDIM 256
#define EDIM 512
#define NB   2
#define NSQ  512
#define NSK  512

typedef _Float16 f16x8 __attribute__((ext_vector_type(8)));
typedef _Float16 h2    __attribute__((ext_vector_type(2)));
typedef __fp16   fp16v2 __attribute__((ext_vector_type(2)));
typedef float    f32x4  __attribute__((ext_vector_type(4)));

// Workspace layout (ushort elements). All weights in 16x16x32 A-frag layout:
// frag[t][s][lane][j8] = W[(s*32 + (lane>>4)*8 + j)*256 + t*16 + (lane&15)]
// Tile stride = S*64*8 ushorts (S=16 -> 8192, S=8 -> 4096).
#define OFF_W2F  0u
#define OFF_W3F  65536u
#define OFF_WQEF 131072u
#define OFF_WKEF 262144u
#define OFF_WCQ  393216u
#define OFF_WCK  524288u
#define OFF_WV2H 655360u     // 256 f16
#define F16_WS_END_BYTES 1312768u

union U8 { f16x8 v; h2 h[4]; };

// packed RTZ f32x2 -> f16x2 (v_cvt_pkrtz_f16_f32)
__device__ __forceinline__ ushort2 f2h2(float x, float y) {
  fp16v2 r = __builtin_amdgcn_cvt_pkrtz(x, y);
  ushort2 u;
  __builtin_memcpy(&u, &r, 4);
  return u;
}
__device__ __forceinline__ float relu_(float x) { return x > 0.f ? x : 0.f; }
__device__ __forceinline__ float softplus_(float x) {
  return fmaxf(x, 0.f) + log1pf(expf(-fabsf(x)));
}

// ---------------------------------------------------------------------------
// K1: shuffle fp32 weights -> f16 MFMA A-frag order via LDS transpose.
// Blocks: 0-7 W2 | 8-15 W3 | 16-31 Wqe | 32-47 Wke |
//         48-55 W1top | 56-63 Wv1top | 64-71 W1bot | 72-79 Wv1bot | 80 Wv2
// ---------------------------------------------------------------------------
__global__ __launch_bounds__(256) void shuffle_weights(
    const float* __restrict__ Wqe, const float* __restrict__ Wke,
    const float* __restrict__ W1,  const float* __restrict__ Wv1,
    const float* __restrict__ W2,  const float* __restrict__ W3,
    const float* __restrict__ Wv2,
    unsigned short* __restrict__ wsb)
{
  __shared__ float sW[32 * 257];   // pad +1: transpose reads 2-way max (free)
  const int bx = blockIdx.x;
  const int t = threadIdx.x;
  if (bx == 80) {
    if (t < 64) {
      float a = Wv2[t * 4 + 0], b = Wv2[t * 4 + 1];
      float c = Wv2[t * 4 + 2], d = Wv2[t * 4 + 3];
      ushort2 lo = f2h2(a, b), hi = f2h2(c, d);
      ushort4 o; o.x = lo.x; o.y = lo.y; o.z = hi.x; o.w = hi.y;
      *(ushort4*)&wsb[OFF_WV2H + t * 4] = o;
    }
    return;
  }
  const float* src; unsigned short* dst; int s; int S;
  if      (bx <  8) { src = W2;          dst = wsb + OFF_W2F;           s = bx;      S = 8;  }
  else if (bx < 16) { src = W3;          dst = wsb + OFF_W3F;           s = bx - 8;  S = 8;  }
  else if (bx < 32) { src = Wqe;         dst = wsb + OFF_WQEF;          s = bx - 16; S = 16; }
  else if (bx < 48) { src = Wke;         dst = wsb + OFF_WKEF;          s = bx - 32; S = 16; }
  else if (bx < 56) { src = W1;          dst = wsb + OFF_WCQ;           s = bx - 48; S = 8;  }
  else if (bx < 64) { src = Wv1;         dst = wsb + OFF_WCQ + 65536u;  s = bx - 56; S = 8;  }
  else if (bx < 72) { src = W1 + 65536;  dst = wsb + OFF_WCK;           s = bx - 64; S = 8;  }
  else              { src = Wv1 + 65536; dst = wsb + OFF_WCK + 65536u;  s = bx - 72; S = 8;  }

  const int kbase = s * 32;
  #pragma unroll
  for (int it = 0; it < 8; ++it) {
    const int f4 = it * 256 + t;
    const int row = f4 >> 6, c4 = (f4 & 63) * 4;
    float4 v = *(const float4*)(src + (size_t)(kbase + row) * 256 + c4);
    sW[row * 257 + c4 + 0] = v.x; sW[row * 257 + c4 + 1] = v.y;
    sW[row * 257 + c4 + 2] = v.z; sW[row * 257 + c4 + 3] = v.w;
  }
  __syncthreads();

  const int wave = t >> 6, lane = t & 63;
  const int n_in = lane & 15, k0 = (lane >> 4) * 8;
  for (int tt = wave * 4; tt < wave * 4 + 4; ++tt) {
    const int n = tt * 16 + n_in;
    float x[8];
    #pragma unroll
    for (int j = 0; j < 8; ++j) x[j] = sW[(k0 + j) * 257 + n];
    ushort2 p0 = f2h2(x[0], x[1]), p1 = f2h2(x[2], x[3]);
    ushort2 p2 = f2h2(x[4], x[5]), p3 = f2h2(x[6], x[7]);
    ushort4 lo; lo.x = p0.x; lo.y = p0.y; lo.z = p1.x; lo.w = p1.y;
    ushort4 hi; hi.x = p2.x; hi.y = p2.y; hi.z = p3.x; hi.w = p3.y;
    unsigned short* o = dst + ((size_t)(tt * S + s) * 64 + lane) * 8;
    *(ushort4*)&o[0] = lo; *(ushort4*)&o[4] = hi;
  }
}

// ---------------------------------------------------------------------------
// K2: encoder + projections (16x16x32 f16 MFMA).
// 512 blocks x 512 threads: (side, rt in 0..63 [16 rows], nh in 0..3).
// GEMM1e (full F, 2 tiles/wave — tile stride 8192 ushorts, the R14 bug was
// using 16384 here) duplicated across the 4 nh blocks; GEMM2e does the nh
// quarter (8 of 32 n-tiles, 1 tile/wave).
// ---------------------------------------------------------------------------
__global__ __launch_bounds__(512) void encoder_kernel(
    const float* __restrict__ query, const float* __restrict__ key,
    const float* __restrict__ bqe,   const float* __restrict__ bke,
    const float* __restrict__ b1,    const float* __restrict__ bv1,
    const unsigned short* __restrict__ WqeF, const unsigned short* __restrict__ WkeF,
    const unsigned short* __restrict__ WcqF, const unsigned short* __restrict__ WckF,
    _Float16* __restrict__ Pq, _Float16* __restrict__ Pk)
{
  __shared__ unsigned short sX[16 * 520];
  __shared__ unsigned short sF[16 * 264];
  __shared__ float sBe[256];
  __shared__ float sBc[512];

  const int bx   = blockIdx.x;
  const int side = bx >> 8;          // 0 = q, 1 = k
  const int idx  = bx & 255;
  const int rt   = idx >> 2;         // 0..63, 16-row group
  const int nh   = idx & 3;          // 0..3, GEMM2e n-quarter
  const int t    = threadIdx.x;

  const float* Xsrc = side ? key : query;
  const unsigned short* WeF = side ? WkeF : WqeF;
  const unsigned short* WcF = side ? WckF : WcqF;
  _Float16* P = side ? Pk : Pq;

  const int wave = t >> 6, lane = t & 63;
  const int l15 = lane & 15, q4 = lane >> 4;

  // GEMM1e A s=0 prefetch (independent of staging). Tile stride 8192.
  const unsigned short* aeb = WeF + ((size_t)(wave * 2) * 16 * 64 + lane) * 8;
  f16x8 afe[2][2];
  #pragma unroll
  for (int ft = 0; ft < 2; ++ft)
    afe[0][ft] = *(const f16x8*)(aeb + ft * 8192);

  // staging: 16 rows x 512 cols, j-interleaved for full coalescing
  {
    const int m = t >> 5, ch = t & 31;
    const float* xr = Xsrc + (size_t)(rt * 16 + m) * EDIM;
    #pragma unroll
    for (int j = 0; j < 4; ++j) {
      const int c = j * 128 + ch * 4;
      float4 v = *(const float4*)(xr + c);
      ushort2 lo = f2h2(v.x, v.y), hi = f2h2(v.z, v.w);
      ushort4 xb; xb.x = lo.x; xb.y = lo.y; xb.z = hi.x; xb.w = hi.y;
      *(ushort4*)&sX[m * 520 + c] = xb;
    }
    if (t < 256) {
      sBe[t]       = side ? bke[t] : bqe[t];
      sBc[t]       = side ? 0.f : b1[t];
      sBc[256 + t] = side ? 0.f : bv1[t];
    }
  }
  __syncthreads();

  // GEMM1e: D[n][m] = sum_k We[k][n] * X[m][k], K=512 (16 s), 2 tiles/wave
  f32x4 acc1[2];
  #pragma unroll
  for (int ft = 0; ft < 2; ++ft) acc1[ft] = (f32x4){0.f, 0.f, 0.f, 0.f};

  #pragma unroll
  for (int s = 0; s < 16; ++s) {
    if (s < 15) {
      #pragma unroll
      for (int ft = 0; ft < 2; ++ft)
        afe[(s + 1) & 1][ft] = *(const f16x8*)(aeb + ft * 8192 + (size_t)(s + 1) * 512);
    }
    f16x8 bfr = *(const f16x8*)&sX[l15 * 520 + s * 32 + q4 * 8];
    #pragma unroll
    for (int ft = 0; ft < 2; ++ft)
      acc1[ft] = __builtin_amdgcn_mfma_f32_16x16x32_f16(afe[s & 1][ft], bfr, acc1[ft], 0, 0, 0);
  }

  // Epilogue 1: F = relu(D + be) -> f16 LDS [m][n]
  #pragma unroll
  for (int ft = 0; ft < 2; ++ft) {
    const int tg = wave * 2 + ft;
    const int n0 = tg * 16 + q4 * 4;
    float4 b4 = *(const float4*)&sBe[n0];
    f32x4 a = acc1[ft];
    ushort2 lo = f2h2(relu_(a[0] + b4.x), relu_(a[1] + b4.y));
    ushort2 hi = f2h2(relu_(a[2] + b4.z), relu_(a[3] + b4.w));
    ushort4 h; h.x = lo.x; h.y = lo.y; h.z = hi.x; h.w = hi.y;
    *(ushort4*)&sF[l15 * 264 + n0] = h;
  }
  __syncthreads();

  // GEMM2e: this block's quarter: tg = nh*8 + wave, 1 tile/wave, K=256 (8 s)
  const int tg2 = nh * 8 + wave;
  const unsigned short* acb = WcF + ((size_t)tg2 * 8 * 64 + lane) * 8;
  f16x8 afc[2];
  afc[0] = *(const f16x8*)(acb);

  f32x4 acc2 = (f32x4){0.f, 0.f, 0.f, 0.f};

  #pragma unroll
  for (int s = 0; s < 8; ++s) {
    if (s < 7)
      afc[(s + 1) & 1] = *(const f16x8*)(acb + (size_t)(s + 1) * 512);
    f16x8 bfr = *(const f16x8*)&sF[l15 * 264 + s * 32 + q4 * 8];
    acc2 = __builtin_amdgcn_mfma_f32_16x16x32_f16(afc[s & 1], bfr, acc2, 0, 0, 0);
  }

  // Epilogue 2: store P[row][n] = f16(D + bias)
  {
    const int n0 = tg2 * 16 + q4 * 4;
    float4 bc = *(const float4*)&sBc[n0];
    const int row = rt * 16 + l15;
    ushort2 lo = f2h2(acc2[0] + bc.x, acc2[1] + bc.y);
    ushort2 hi = f2h2(acc2[2] + bc.z, acc2[3] + bc.w);
    ushort4 o; o.x = lo.x; o.y = lo.y; o.z = hi.x; o.w = hi.y;
    *(ushort4*)((unsigned short*)P + (size_t)row * 512 + n0) = o;
  }
}

// ---------------------------------------------------------------------------
// K3: fused pair kernel — R12 exact (best measured: 169.2 us).
// 512 threads = 8 waves; wave w owns n-tiles {2w,2w+1}, all 64 m (acc 2x4).
// Pad-264 rows; A-loads and B ds_reads one-step register-prefetched.
// Dedicated sRed (4 barriers), split fdot2, late variance store.
// launch_bounds(512,4): 128-reg budget fits VGPR 60 + AGPR 32 (R3/R13:
// tighter bounds spill — 421 MB scratch at (512,6); R10: bigger wave
// tiles collapse occupancy). 2 blocks/CU is this structure's plateau.
// ---------------------------------------------------------------------------
__global__ __launch_bounds__(512, 4) void pair_kernel(
    const _Float16* __restrict__ Pq, const _Float16* __restrict__ Pk,
    const unsigned short* __restrict__ W2F, const unsigned short* __restrict__ W3F,
    const float* __restrict__ b2, const float* __restrict__ b3,
    const float* __restrict__ Wf, const float* __restrict__ bfp,
    const unsigned short* __restrict__ Wv2H, const float* __restrict__ bv2p,
    float* __restrict__ out)
{
  __shared__ __align__(16) unsigned char smem[38912];
  unsigned short* sXH = (unsigned short*)smem;        // 64*264 f16 = 33792 B
  float* sB2  = (float*)(smem + 33792);               // 1024 B
  float* sB3  = (float*)(smem + 34816);               // 1024 B
  float* sWf  = (float*)(smem + 35840);               // 1024 B
  float* sRed = (float*)(smem + 36864);               // 8*64*4 = 2048 B (own)

  const int kt = blockIdx.x, qy = blockIdx.y, bz = blockIdx.z;
  const int t = threadIdx.x;
  const _Float16* qpRow = Pq + (size_t)(bz * NSQ + qy) * 512;

  const int wave = t >> 6, lane = t & 63;
  const int l15 = lane & 15, q4 = lane >> 4;

  // A-fragment bases (n-tiles 2w, 2w+1), s-stride 512 ushorts.
  const unsigned short* a2base = W2F + ((size_t)(wave * 2) * 8 * 64 + lane) * 8;
  const unsigned short* a3base = W3F + ((size_t)(wave * 2) * 8 * 64 + lane) * 8;

  // Issue s=0 A-loads for GEMM1 before staging.
  f16x8 afd[2][2];
  afd[0][0] = *(const f16x8*)(a2base);
  afd[0][1] = *(const f16x8*)(a2base + 8 * 64 * 8);

  // --- staging: X1 = relu(qp+kp) (packed f16, pad-264) + variance fdot2 ---
  float vp0 = 0.f, vp1 = 0.f;
  {
    const int m   = t >> 3;     // 0..63 pair row
    const int sub = t & 7;      // 0..7
    const _Float16* kpRow = Pk + (size_t)(bz * NSK + kt * 64 + m) * 512;
    const f16x8 z8 = {0, 0, 0, 0, 0, 0, 0, 0};
    #pragma unroll
    for (int it = 0; it < 4; ++it) {
      const int c = it * 64 + sub * 8;
      f16x8 q8 = *(const f16x8*)(qpRow + c);
      f16x8 k8 = *(const f16x8*)(kpRow + c);
      f16x8 r  = __builtin_elementwise_max(q8 + k8, z8);
      *(f16x8*)&sXH[m * 264 + c] = r;
      f16x8 a8 = *(const f16x8*)(qpRow + 256 + c);
      f16x8 v8 = *(const f16x8*)(kpRow + 256 + c);
      U8 ar; ar.v = __builtin_elementwise_max(a8 + v8, z8);
      U8 w8; w8.v = *(const f16x8*)((const _Float16*)Wv2H + c);
      vp0 = __builtin_amdgcn_fdot2(ar.h[0], w8.h[0], vp0, false);
      vp1 = __builtin_amdgcn_fdot2(ar.h[1], w8.h[1], vp1, false);
      vp0 = __builtin_amdgcn_fdot2(ar.h[2], w8.h[2], vp0, false);
      vp1 = __builtin_amdgcn_fdot2(ar.h[3], w8.h[3], vp1, false);
    }
    if (t < 256) { sB2[t] = b2[t]; sB3[t] = b3[t]; sWf[t] = Wf[t]; }
  }
  __syncthreads();

  // --- GEMM1: D1[n][m] = sum_k W2[k][n] * X1[m][k], A+B prefetched ---
  f32x4 acc[2][4];
  #pragma unroll
  for (int ft = 0; ft < 2; ++ft)
    #pragma unroll
    for (int pt = 0; pt < 4; ++pt)
      acc[ft][pt] = (f32x4){0.f, 0.f, 0.f, 0.f};

  f16x8 bcur[4], bnxt[4];
  #pragma unroll
  for (int pt = 0; pt < 4; ++pt)
    bcur[pt] = *(const f16x8*)&sXH[(pt * 16 + l15) * 264 + q4 * 8];

  #pragma unroll
  for (int s = 0; s < 8; ++s) {
    if (s < 7) {
      afd[(s + 1) & 1][0] = *(const f16x8*)(a2base + (size_t)(s + 1) * 512);
      afd[(s + 1) & 1][1] = *(const f16x8*)(a2base + 8 * 64 * 8 + (size_t)(s + 1) * 512);
      #pragma unroll
      for (int pt = 0; pt < 4; ++pt)
        bnxt[pt] = *(const f16x8*)&sXH[(pt * 16 + l15) * 264 + (s + 1) * 32 + q4 * 8];
    }
    #pragma unroll
    for (int ft = 0; ft < 2; ++ft)
      #pragma unroll
      for (int pt = 0; pt < 4; ++pt)
        acc[ft][pt] = __builtin_amdgcn_mfma_f32_16x16x32_f16(afd[s & 1][ft], bcur[pt], acc[ft][pt], 0, 0, 0);
    #pragma unroll
    for (int pt = 0; pt < 4; ++pt) bcur[pt] = bnxt[pt];
  }
  __syncthreads();   // all X1 reads done before overwrite

  // Prefetch GEMM2 s=0 A-frags during epilogue 1.
  afd[0][0] = *(const f16x8*)(a3base);
  afd[0][1] = *(const f16x8*)(a3base + 8 * 64 * 8);

  // --- Epilogue 1: H1 = relu(D1 + b2) -> f16, same LDS (pad-264) ---
  #pragma unroll
  for (int ft = 0; ft < 2; ++ft) {
    const int tg = wave * 2 + ft;
    const int n0 = tg * 16 + q4 * 4;
    float4 b4 = *(const float4*)&sB2[n0];
    #pragma unroll
    for (int pt = 0; pt < 4; ++pt) {
      const int mr = pt * 16 + l15;
      f32x4 a = acc[ft][pt];
      ushort2 lo = f2h2(relu_(a[0] + b4.x), relu_(a[1] + b4.y));
      ushort2 hi = f2h2(relu_(a[2] + b4.z), relu_(a[3] + b4.w));
      ushort4 h; h.x = lo.x; h.y = lo.y; h.z = hi.x; h.w = hi.y;
      *(ushort4*)&sXH[mr * 264 + n0] = h;
    }
  }
  __syncthreads();

  // --- GEMM2: D2[n][m] = sum_k W3[k][n] * H1[m][k], A+B prefetched ---
  f32x4 acc2[2][4];
  #pragma unroll
  for (int ft = 0; ft < 2; ++ft)
    #pragma unroll
    for (int pt = 0; pt < 4; ++pt)
      acc2[ft][pt] = (f32x4){0.f, 0.f, 0.f, 0.f};

  #pragma unroll
  for (int pt = 0; pt < 4; ++pt)
    bcur[pt] = *(const f16x8*)&sXH[(pt * 16 + l15) * 264 + q4 * 8];

  #pragma unroll
  for (int s = 0; s < 8; ++s) {
    if (s < 7) {
      afd[(s + 1) & 1][0] = *(const f16x8*)(a3base + (size_t)(s + 1) * 512);
      afd[(s + 1) & 1][1] = *(const f16x8*)(a3base + 8 * 64 * 8 + (size_t)(s + 1) * 512);
      #pragma unroll
      for (int pt = 0; pt < 4; ++pt)
        bnxt[pt] = *(const f16x8*)&sXH[(pt * 16 + l15) * 264 + (s + 1) * 32 + q4 * 8];
    }
    #pragma unroll
    for (int ft = 0; ft < 2; ++ft)
      #pragma unroll
      for (int pt = 0; pt < 4; ++pt)
        acc2[ft][pt] = __builtin_amdgcn_mfma_f32_16x16x32_f16(afd[s & 1][ft], bcur[pt], acc2[ft][pt], 0, 0, 0);
    #pragma unroll
    for (int pt = 0; pt < 4; ++pt) bcur[pt] = bnxt[pt];
  }

  // --- variance head: reduce + store (off the staging critical path) ---
  {
    float v = vp0 + vp1;
    v += __shfl_xor(v, 1, 64);
    v += __shfl_xor(v, 2, 64);
    v += __shfl_xor(v, 4, 64);
    if ((t & 7) == 0) {
      const int m = t >> 3;
      const size_t o = (size_t)(bz * NSQ + qy) * NSK + kt * 64 + m;
      out[(size_t)NB * NSQ * NSK + o] = softplus_(v + bv2p[0]);
    }
  }

  // --- Final epilogue: logit partials over this wave's 32 n-cols ---
  float p[4] = {0.f, 0.f, 0.f, 0.f};
  #pragma unroll
  for (int ft = 0; ft < 2; ++ft) {
    const int tg = wave * 2 + ft;
    const int n0 = tg * 16 + q4 * 4;
    float4 b4 = *(const float4*)&sB3[n0];
    float4 w4 = *(const float4*)&sWf[n0];
    #pragma unroll
    for (int pt = 0; pt < 4; ++pt) {
      f32x4 a = acc2[ft][pt];
      p[pt] += relu_(a[0] + b4.x) * w4.x + relu_(a[1] + b4.y) * w4.y
             + relu_(a[2] + b4.z) * w4.z + relu_(a[3] + b4.w) * w4.w;
    }
  }
  // sRed is its own buffer — no barrier needed before writing it.
  #pragma unroll
  for (int pt = 0; pt < 4; ++pt) {
    float v = p[pt];
    v += __shfl_xor(v, 16, 64);
    v += __shfl_xor(v, 32, 64);
    if (lane < 16) sRed[wave * 64 + pt * 16 + lane] = v;
  }
  __syncthreads();

  if (t < 64) {
    const size_t o = (size_t)(bz * NSQ + qy) * NSK + kt * 64 + t;
    float lg = bfp[0];
    #pragma unroll
    for (int w = 0; w < 8; ++w) lg += sRed[w * 64 + t];
    out[o] = lg;
  }
}

// ---------------------------------------------------------------------------
extern "C" void kernel_launch(void* const* d_in, const int* in_sizes, int n_in,
                              void* d_out, int out_size, void* d_ws, size_t ws_size,
                              hipStream_t stream)
{
  (void)in_sizes; (void)n_in; (void)out_size; (void)ws_size;
  const float* query = (const float*)d_in[0];
  const float* key   = (const float*)d_in[1];
  const float* Wqe   = (const float*)d_in[2];
  const float* bqe   = (const float*)d_in[3];
  const float* Wke   = (const float*)d_in[4];
  const float* bke   = (const float*)d_in[5];
  const float* W1    = (const float*)d_in[6];
  const float* b1    = (const float*)d_in[7];
  const float* W2    = (const float*)d_in[8];
  const float* b2    = (const float*)d_in[9];
  const float* W3    = (const float*)d_in[10];
  const float* b3    = (const float*)d_in[11];
  const float* Wf    = (const float*)d_in[12];
  const float* bf    = (const float*)d_in[13];
  const float* Wv1   = (const float*)d_in[14];
  const float* bv1   = (const float*)d_in[15];
  const float* Wv2   = (const float*)d_in[16];
  const float* bv2   = (const float*)d_in[17];

  unsigned short* wsb = (unsigned short*)d_ws;
  _Float16* Pq = (_Float16*)((char*)d_ws + F16_WS_END_BYTES);   // [1024][512] f16
  _Float16* Pk = Pq + (size_t)1024 * 512;                       // [1024][512] f16
  float* out = (float*)d_out;

  shuffle_weights<<<81, 256, 0, stream>>>(Wqe, Wke, W1, Wv1, W2, W3, Wv2, wsb);
  encoder_kernel<<<512, 512, 0, stream>>>(query, key, bqe, bke, b1, bv1,
      wsb + OFF_WQEF, wsb + OFF_WKEF, wsb + OFF_WCQ, wsb + OFF_WCK, Pq, Pk);
  pair_kernel<<<dim3(NSK / 64, NSQ, NB), 512, 0, stream>>>(Pq, Pk,
      wsb + OFF_W2F, wsb + OFF_W3F, b2, b3, Wf, bf, wsb + OFF_WV2H, bv2, out);
}